// Round 1
// baseline (761.179 us; speedup 1.0000x reference)
//
#include <hip/hip_runtime.h>

#define B_ 16
#define T_ 400
#define NH_ 100
#define NB_ 65
#define BLK_ 160
#define SR_ 16000
#define N_ 64000           // T_*BLK_
#define REV_ 16000
#define IMPAD_ 16128       // REV_ rounded up to multiple of 256
#define SIGSTRIDE_ 81664   // IMPAD_ + 65536 (front zero pad + signal + tail pad)
#define SIGOFF_ 16128

// ---------------- K1: fp64 prefix of per-block phase increments ----------------
__global__ __launch_bounds__(512) void k_prefix(const float* __restrict__ pitch,
                                                double* __restrict__ Pv,
                                                double* __restrict__ Xv) {
  __shared__ double s[512];
  const int b = blockIdx.x, t = threadIdx.x;
  double x = 0.0;
  if (t < T_) x = (double)pitch[b * T_ + t] * (6.283185307179586476925287 / (double)SR_);
  s[t] = x;
  __syncthreads();
  for (int off = 1; off < 512; off <<= 1) {
    double v = (t >= off) ? s[t - off] : 0.0;
    __syncthreads();
    s[t] += v;
    __syncthreads();
  }
  if (t < T_) {
    Xv[b * T_ + t] = x;                    // x_t
    Pv[b * T_ + t] = (s[t] - x) * 160.0;   // 160 * sum_{t'<t} x_{t'}
  }
}

// ---------------- K2: per-(b,t) harmonic synth + filtered noise ----------------
__global__ __launch_bounds__(160) void k_synth(
    const float* __restrict__ pitch, const float* __restrict__ tamp,
    const float* __restrict__ harmo, const float* __restrict__ nfilt,
    const float* __restrict__ noise, const double* __restrict__ Pv,
    const double* __restrict__ Xv, float* __restrict__ sigpad) {
  const int bt = blockIdx.x, b = bt / T_, t = bt - b * T_;
  const int tid = threadIdx.x;
  __shared__ float amp[NH_], sbase[NH_], sstep[NH_];
  __shared__ float a_s[NB_], ctab[128], ir_s[128], imp_s[BLK_], noi_s[BLK_], red[128];

  const float pv = pitch[b * T_ + t];
  // phase A: loads + raw amps + cos table
  if (tid < 128) ctab[tid] = cosf((float)tid * 0.049087385212340526f);  // 2pi/128
  if (tid < NB_) a_s[tid] = nfilt[bt * NB_ + tid];
  noi_s[tid] = noise[bt * BLK_ + tid];
  if (tid < NH_) {
    float ha = harmo[(b * NH_ + tid) * T_ + t];
    float aa = (pv * (float)(tid + 1) < 8000.0f ? 1.0f : 0.0f) + 1e-4f;
    amp[tid] = ha * aa;
  }
  __syncthreads();
  // phase B: 128-point irfft via direct cosine sum; reduction staging
  if (tid < 128) {
    float sum = 0.f;
    for (int k = 1; k < 64; ++k) sum = fmaf(a_s[k], ctab[(k * tid) & 127], sum);
    float v = a_s[0] + ((tid & 1) ? -a_s[64] : a_s[64]) + 2.f * sum;
    ir_s[tid] = v * (1.0f / 128.0f);
    red[tid] = (tid < NH_) ? amp[tid] : 0.f;
  }
  __syncthreads();
  for (int off = 64; off >= 1; off >>= 1) {
    if (tid < off) red[tid] += red[tid + off];
    __syncthreads();
  }
  // phase D: normalize amps, fp64 phase bases/steps reduced mod 2pi, windowed impulse
  const float scale = tamp[b * T_ + t] / red[0];
  if (tid < NH_) {
    amp[tid] *= scale;
    const double h = (double)(tid + 1);
    double vb = h * Pv[b * T_ + t];
    vb -= floor(vb * 0.15915494309189533577) * 6.2831853071795864769;
    sbase[tid] = (float)vb;
    double vs = h * Xv[b * T_ + t];
    vs -= floor(vs * 0.15915494309189533577) * 6.2831853071795864769;
    sstep[tid] = (float)vs;
  }
  {
    float v;
    if (tid < 64)      v = (0.5f - 0.5f * ctab[tid + 64]) * ir_s[tid];
    else if (tid < 96) v = 0.f;
    else               v = (0.5f - 0.5f * ctab[tid - 96]) * ir_s[tid - 32];
    imp_s[tid] = v;
  }
  __syncthreads();
  // phase E: 160-tap causal conv + 100-harmonic additive synthesis
  float nf = 0.f;
  for (int j = 0; j <= tid; ++j) nf = fmaf(noi_s[j], imp_s[tid - j], nf);
  const float fi = (float)(tid + 1);
  float acc = 0.f;
#pragma unroll 4
  for (int h = 0; h < NH_; ++h) {
    float ph = fmaf(fi, sstep[h], sbase[h]);
    ph = fmaf(-floorf(ph * 0.15915494f), 6.2831853f, ph);
    acc = fmaf(amp[h], __sinf(ph), acc);
  }
  sigpad[(size_t)b * SIGSTRIDE_ + SIGOFF_ + t * BLK_ + tid] = acc + nf;
}

// ---------------- K3: reverb impulse ----------------
__global__ void k_imp(const float* __restrict__ rn, const float* __restrict__ dec,
                      const float* __restrict__ wet, float* __restrict__ imp) {
  const int l = blockIdx.x * 256 + threadIdx.x;
  if (l >= IMPAD_) return;
  float v;
  if (l >= REV_) {
    v = 0.f;
  } else {
    const float a = log1pf(expf(-dec[0]));
    const float sg = 1.f / (1.f + expf(-wet[0]));
    v = rn[l] * expf(-a * ((float)l / (float)SR_) * 500.0f) * sg;
    if (l == 0) v = 1.0f;
  }
  imp[l] = v;
}

// ---------------- K4: reverb convolution (16000-tap) ----------------
// out[b,p] = sum_{l} imp[l] * sig[b, p-l], front/tail zero-padded signal.
__global__ __launch_bounds__(256) void k_conv(const float* __restrict__ sigpad,
                                              const float* __restrict__ imp,
                                              float* __restrict__ out) {
  const int b = blockIdx.y;
  const int P0 = blockIdx.x * 2048;
  const float* sp = sigpad + (size_t)b * SIGSTRIDE_;
  __shared__ float imp_s[256];
  __shared__ float sig_s[2592];  // 2303 entries, padded j -> j + j/8 (stride-9 reads)
  const int tid = threadIdx.x;
  float acc[8] = {0.f, 0.f, 0.f, 0.f, 0.f, 0.f, 0.f, 0.f};

  for (int L0 = 0; L0 < IMPAD_; L0 += 256) {
    __syncthreads();
    imp_s[tid] = imp[L0 + tid];
    const int G0 = SIGOFF_ + P0 - L0 - 255;
#pragma unroll
    for (int k = 0; k < 9; ++k) {
      int j = tid + (k << 8);
      if (j < 2303) sig_s[j + (j >> 3)] = sp[G0 + j];
    }
    __syncthreads();

    const int base = tid * 8 + 255;
    float buf[15];
#pragma unroll
    for (int i = 0; i < 15; ++i) { int j = base + i - 7; buf[i] = sig_s[j + (j >> 3)]; }
#pragma unroll 1
    for (int g = 0; g < 32; ++g) {
#pragma unroll
      for (int s = 0; s < 8; ++s) {
        const float ib = imp_s[(g << 3) + s];
#pragma unroll
        for (int r = 0; r < 8; ++r) acc[r] = fmaf(ib, buf[7 + r - s], acc[r]);
      }
      if (g < 31) {
#pragma unroll
        for (int i = 6; i >= 0; --i) buf[i + 8] = buf[i];
#pragma unroll
        for (int i = 0; i < 8; ++i) {
          int j = base - ((g + 1) << 3) + i - 7;
          buf[i] = sig_s[j + (j >> 3)];
        }
      }
    }
  }
#pragma unroll
  for (int r = 0; r < 8; ++r) {
    const int p = P0 + tid * 8 + r;
    if (p < N_) out[(size_t)b * N_ + p] = acc[r];
  }
}

extern "C" void kernel_launch(void* const* d_in, const int* in_sizes, int n_in,
                              void* d_out, int out_size, void* d_ws, size_t ws_size,
                              hipStream_t stream) {
  const float* pitch = (const float*)d_in[0];
  const float* tamp  = (const float*)d_in[1];
  const float* harmo = (const float*)d_in[2];
  const float* nfilt = (const float*)d_in[3];
  const float* noise = (const float*)d_in[4];
  const float* rn    = (const float*)d_in[5];
  const float* dec   = (const float*)d_in[6];
  const float* wet   = (const float*)d_in[7];

  char* ws = (char*)d_ws;
  float*  sigpad = (float*)ws;                                              // 16*81664 f32
  float*  imp    = (float*)(ws + (size_t)B_ * SIGSTRIDE_ * 4);              // 16128 f32
  double* Pv     = (double*)(ws + (size_t)B_ * SIGSTRIDE_ * 4 + IMPAD_ * 4);
  double* Xv     = (double*)(ws + (size_t)B_ * SIGSTRIDE_ * 4 + IMPAD_ * 4 + (size_t)B_ * T_ * 8);
  float* out = (float*)d_out;

  hipMemsetAsync(sigpad, 0, (size_t)B_ * SIGSTRIDE_ * 4, stream);
  k_prefix<<<dim3(B_), dim3(512), 0, stream>>>(pitch, Pv, Xv);
  k_synth<<<dim3(B_ * T_), dim3(160), 0, stream>>>(pitch, tamp, harmo, nfilt, noise, Pv, Xv, sigpad);
  k_imp<<<dim3((IMPAD_ + 255) / 256), dim3(256), 0, stream>>>(rn, dec, wet, imp);
  k_conv<<<dim3(32, B_), dim3(256), 0, stream>>>(sigpad, imp, out);
}

// Round 2
// 195.666 us; speedup vs baseline: 3.8902x; 3.8902x over previous
//
#include <hip/hip_runtime.h>

#define B_ 16
#define T_ 400
#define NH_ 100
#define NB_ 65
#define BLK_ 160
#define SR_ 16000
#define N_ 64000           // T_*BLK_
#define REV_ 16000
#define IMPAD_ 16128       // REV_ rounded up (zero tail)
#define KPAD_ 16128        // front zero pad of signal (multiple of 32)
#define KTOT_ 80128        // KPAD_ + N_
#define NT_ 1014           // Toeplitz frag table entries (t = d/16 + 6, t in [0,1013])
#define KSPLIT_ 4
#define STEPS_ 126         // 504/KSPLIT_

typedef __attribute__((ext_vector_type(8))) short bf16x8;
typedef __attribute__((ext_vector_type(4))) float f32x4;

static __device__ __forceinline__ unsigned short f2bf(float f) {
  unsigned u = __float_as_uint(f);
  unsigned r = (u + 0x7fffu + ((u >> 16) & 1u)) >> 16;
  return (unsigned short)r;
}
static __device__ __forceinline__ float bf2f(unsigned short h) {
  return __uint_as_float(((unsigned)h) << 16);
}

// ---------------- K1: fp64 prefix of per-block phase increments ----------------
__global__ __launch_bounds__(512) void k_prefix(const float* __restrict__ pitch,
                                                double* __restrict__ Pv,
                                                double* __restrict__ Xv) {
  __shared__ double s[512];
  const int b = blockIdx.x, t = threadIdx.x;
  double x = 0.0;
  if (t < T_) x = (double)pitch[b * T_ + t] * (6.283185307179586476925287 / (double)SR_);
  s[t] = x;
  __syncthreads();
  for (int off = 1; off < 512; off <<= 1) {
    double v = (t >= off) ? s[t - off] : 0.0;
    __syncthreads();
    s[t] += v;
    __syncthreads();
  }
  if (t < T_) {
    Xv[b * T_ + t] = x;
    Pv[b * T_ + t] = (s[t] - x) * 160.0;
  }
}

// ---------------- K2: per-(b,t) harmonic synth + filtered noise -> packed bf16 hi/lo ----------------
__global__ __launch_bounds__(160) void k_synth(
    const float* __restrict__ pitch, const float* __restrict__ tamp,
    const float* __restrict__ harmo, const float* __restrict__ nfilt,
    const float* __restrict__ noise, const double* __restrict__ Pv,
    const double* __restrict__ Xv, unsigned short* __restrict__ PH,
    unsigned short* __restrict__ PL) {
  const int bt = blockIdx.x, b = bt / T_, t = bt - b * T_;
  const int tid = threadIdx.x;
  __shared__ float amp[NH_], sbase[NH_], sstep[NH_];
  __shared__ float a_s[NB_], ctab[128], ir_s[128], imp_s[BLK_], noi_s[BLK_], red[128];

  const float pv = pitch[b * T_ + t];
  if (tid < 128) ctab[tid] = cosf((float)tid * 0.049087385212340526f);  // 2pi/128
  if (tid < NB_) a_s[tid] = nfilt[bt * NB_ + tid];
  noi_s[tid] = noise[bt * BLK_ + tid];
  if (tid < NH_) {
    float ha = harmo[(b * NH_ + tid) * T_ + t];
    float aa = (pv * (float)(tid + 1) < 8000.0f ? 1.0f : 0.0f) + 1e-4f;
    amp[tid] = ha * aa;
  }
  __syncthreads();
  if (tid < 128) {
    float sum = 0.f;
    for (int k = 1; k < 64; ++k) sum = fmaf(a_s[k], ctab[(k * tid) & 127], sum);
    float v = a_s[0] + ((tid & 1) ? -a_s[64] : a_s[64]) + 2.f * sum;
    ir_s[tid] = v * (1.0f / 128.0f);
    red[tid] = (tid < NH_) ? amp[tid] : 0.f;
  }
  __syncthreads();
  for (int off = 64; off >= 1; off >>= 1) {
    if (tid < off) red[tid] += red[tid + off];
    __syncthreads();
  }
  const float scale = tamp[b * T_ + t] / red[0];
  if (tid < NH_) {
    amp[tid] *= scale;
    const double h = (double)(tid + 1);
    double vb = h * Pv[b * T_ + t];
    vb -= floor(vb * 0.15915494309189533577) * 6.2831853071795864769;
    sbase[tid] = (float)vb;
    double vs = h * Xv[b * T_ + t];
    vs -= floor(vs * 0.15915494309189533577) * 6.2831853071795864769;
    sstep[tid] = (float)vs;
  }
  {
    float v;
    if (tid < 64)      v = (0.5f - 0.5f * ctab[tid + 64]) * ir_s[tid];
    else if (tid < 96) v = 0.f;
    else               v = (0.5f - 0.5f * ctab[tid - 96]) * ir_s[tid - 32];
    imp_s[tid] = v;
  }
  __syncthreads();
  float nf = 0.f;
  for (int j = 0; j <= tid; ++j) nf = fmaf(noi_s[j], imp_s[tid - j], nf);
  const float fi = (float)(tid + 1);
  float acc = 0.f;
#pragma unroll 4
  for (int h = 0; h < NH_; ++h) {
    float ph = fmaf(fi, sstep[h], sbase[h]);
    ph = fmaf(-floorf(ph * 0.15915494f), 6.2831853f, ph);
    acc = fmaf(amp[h], __sinf(ph), acc);
  }
  const float v = acc + nf;
  const unsigned k = (unsigned)(KPAD_ + t * BLK_ + tid);
  const unsigned off = ((k >> 3) << 7) + ((unsigned)b << 3) + (k & 7u);
  const unsigned short h = f2bf(v);
  PH[off] = h;
  PL[off] = f2bf(v - bf2f(h));
}

// ---------------- K3: reverb impulse (fp32, zero tail to IMPAD_) ----------------
__global__ void k_imp(const float* __restrict__ rn, const float* __restrict__ dec,
                      const float* __restrict__ wet, float* __restrict__ imp) {
  const int l = blockIdx.x * 256 + threadIdx.x;
  if (l >= IMPAD_) return;
  float v;
  if (l >= REV_) {
    v = 0.f;
  } else {
    const float a = log1pf(expf(-dec[0]));
    const float sg = 1.f / (1.f + expf(-wet[0]));
    v = rn[l] * expf(-a * ((float)l / (float)SR_) * 500.0f) * sg;
    if (l == 0) v = 1.0f;
  }
  imp[l] = v;
}

// ---------------- K4: build Toeplitz A-fragment table (hi/lo bf16) ----------------
// FRAG[t][lane][j] = imp[(t-6)*16 + (lane&15) - 8*(lane>>4) - j]
__global__ __launch_bounds__(512) void k_fragbuild(const float* __restrict__ imp,
                                                   unsigned short* __restrict__ FH,
                                                   unsigned short* __restrict__ FL) {
  const int t = blockIdx.x, tid = threadIdx.x;
  const int lane = tid >> 3, j = tid & 7;
  const int idx = (t - 6) * 16 + (lane & 15) - ((lane >> 4) << 3) - j;
  const float v = (idx >= 0 && idx < REV_) ? imp[idx] : 0.f;
  const unsigned short h = f2bf(v);
  FH[t * 512 + tid] = h;
  FL[t * 512 + tid] = f2bf(v - bf2f(h));
}

// ---------------- K5: reverb as Toeplitz MFMA GEMM ----------------
// C[p][b] += sum_x imp[p-x]*sig[x][b]; one wave per 128 outputs, K split 4-way.
__global__ __launch_bounds__(64) void k_mconv(const bf16x8* __restrict__ FH,
                                              const bf16x8* __restrict__ FL,
                                              const bf16x8* __restrict__ PH,
                                              const bf16x8* __restrict__ PL,
                                              float* __restrict__ out) {
  const int w = blockIdx.x;          // 0..499
  const int s = blockIdx.y;          // 0..KSPLIT_-1
  const int lane = threadIdx.x;      // 0..63
  const int P0w = w << 7;
  const int T0 = 1006 - 252 * s;     // frag-table index at i=0, m=0

  const bf16x8* fh = FH + lane;      // + t*64 per table entry
  const bf16x8* fl = FL + lane;
  bf16x8 ahi[8], alo[8];
#pragma unroll
  for (int m = 0; m < 8; ++m) {
    ahi[m] = fh[(T0 + m) * 64];
    alo[m] = fl[(T0 + m) * 64];
  }
  f32x4 acc[8];
#pragma unroll
  for (int m = 0; m < 8; ++m) acc[m] = (f32x4){0.f, 0.f, 0.f, 0.f};

  // per-lane B pointers into packed signal: unit = bf16x8 (16B)
  const int K0 = P0w - REV_ + s * (STEPS_ * 32) + KPAD_;  // k0 at i=0
  const bf16x8* ph = PH + ((lane >> 4) << 4) + (lane & 15);
  const bf16x8* pl = PL + ((lane >> 4) << 4) + (lane & 15);

  bf16x8 bhi = ph[K0 << 1], blo = pl[K0 << 1];
  for (int i = 0; i < STEPS_; ++i) {
    bf16x8 nbh, nbl, na0h, na1h, na0l, na1l;
    const int tn = T0 - 2 * (i + 1);
    if (i < STEPS_ - 1) {
      const int k2 = (K0 + ((i + 1) << 5)) << 1;
      nbh = ph[k2]; nbl = pl[k2];
      na0h = fh[tn * 64]; na1h = fh[(tn + 1) * 64];
      na0l = fl[tn * 64]; na1l = fl[(tn + 1) * 64];
    }
#pragma unroll
    for (int m = 0; m < 8; ++m) {
      acc[m] = __builtin_amdgcn_mfma_f32_16x16x32_bf16(ahi[m], bhi, acc[m], 0, 0, 0);
      acc[m] = __builtin_amdgcn_mfma_f32_16x16x32_bf16(ahi[m], blo, acc[m], 0, 0, 0);
      acc[m] = __builtin_amdgcn_mfma_f32_16x16x32_bf16(alo[m], bhi, acc[m], 0, 0, 0);
    }
    if (i < STEPS_ - 1) {
#pragma unroll
      for (int m = 7; m >= 2; --m) { ahi[m] = ahi[m - 2]; alo[m] = alo[m - 2]; }
      ahi[0] = na0h; ahi[1] = na1h;
      alo[0] = na0l; alo[1] = na1l;
      bhi = nbh; blo = nbl;
    }
  }

  const int b = lane & 15, hi2 = lane >> 4;
#pragma unroll
  for (int m = 0; m < 8; ++m) {
    const int p = P0w + (m << 4) + (hi2 << 2);
    float* o = out + b * N_ + p;
    atomicAdd(o + 0, acc[m][0]);
    atomicAdd(o + 1, acc[m][1]);
    atomicAdd(o + 2, acc[m][2]);
    atomicAdd(o + 3, acc[m][3]);
  }
}

extern "C" void kernel_launch(void* const* d_in, const int* in_sizes, int n_in,
                              void* d_out, int out_size, void* d_ws, size_t ws_size,
                              hipStream_t stream) {
  const float* pitch = (const float*)d_in[0];
  const float* tamp  = (const float*)d_in[1];
  const float* harmo = (const float*)d_in[2];
  const float* nfilt = (const float*)d_in[3];
  const float* noise = (const float*)d_in[4];
  const float* rn    = (const float*)d_in[5];
  const float* dec   = (const float*)d_in[6];
  const float* wet   = (const float*)d_in[7];

  char* ws = (char*)d_ws;
  size_t off = 0;
  float* imp = (float*)(ws + off);            off += (size_t)IMPAD_ * 4;          // 64512
  unsigned short* PH = (unsigned short*)(ws + off); off += (size_t)KTOT_ * 16 * 2; // 2564096
  unsigned short* PL = (unsigned short*)(ws + off); off += (size_t)KTOT_ * 16 * 2;
  unsigned short* FH = (unsigned short*)(ws + off); off += (size_t)NT_ * 512 * 2;  // 1038336
  unsigned short* FL = (unsigned short*)(ws + off); off += (size_t)NT_ * 512 * 2;
  double* Pv = (double*)(ws + off);           off += (size_t)B_ * T_ * 8;
  double* Xv = (double*)(ws + off);           off += (size_t)B_ * T_ * 8;
  float* out = (float*)d_out;

  // zero the front-padded packed signal (both hi and lo, contiguous) and the output
  hipMemsetAsync(PH, 0, (size_t)KTOT_ * 16 * 2 * 2, stream);
  hipMemsetAsync(out, 0, (size_t)out_size * 4, stream);

  k_prefix<<<dim3(B_), dim3(512), 0, stream>>>(pitch, Pv, Xv);
  k_imp<<<dim3((IMPAD_ + 255) / 256), dim3(256), 0, stream>>>(rn, dec, wet, imp);
  k_synth<<<dim3(B_ * T_), dim3(160), 0, stream>>>(pitch, tamp, harmo, nfilt, noise, Pv, Xv, PH, PL);
  k_fragbuild<<<dim3(NT_), dim3(512), 0, stream>>>(imp, FH, FL);
  k_mconv<<<dim3(500, KSPLIT_), dim3(64), 0, stream>>>(
      (const bf16x8*)FH, (const bf16x8*)FL, (const bf16x8*)PH, (const bf16x8*)PL, out);
}

// Round 3
// 141.839 us; speedup vs baseline: 5.3665x; 1.3795x over previous
//
#include <hip/hip_runtime.h>

#define B_ 16
#define T_ 400
#define NH_ 100
#define NB_ 65
#define BLK_ 160
#define SR_ 16000
#define N_ 64000           // T_*BLK_
#define REV_ 16000
#define KPAD_ 16128        // front zero pad of signal (multiple of 32)
#define KTOT_ 80128        // KPAD_ + N_
#define NT_ 1014           // Toeplitz frag table entries
#define KSPLIT_ 4
#define STEPS_ 126         // 504/KSPLIT_

typedef __attribute__((ext_vector_type(8))) short bf16x8;
typedef __attribute__((ext_vector_type(4))) float f32x4;

static __device__ __forceinline__ unsigned short f2bf(float f) {
  unsigned u = __float_as_uint(f);
  unsigned r = (u + 0x7fffu + ((u >> 16) & 1u)) >> 16;
  return (unsigned short)r;
}
static __device__ __forceinline__ float bf2f(unsigned short h) {
  return __uint_as_float(((unsigned)h) << 16);
}

// ---------------- K1: fp64 prefix of per-block phase increments ----------------
__global__ __launch_bounds__(512) void k_prefix(const float* __restrict__ pitch,
                                                double* __restrict__ Pv,
                                                double* __restrict__ Xv) {
  __shared__ double s[512];
  const int b = blockIdx.x, t = threadIdx.x;
  double x = 0.0;
  if (t < T_) x = (double)pitch[b * T_ + t] * (6.283185307179586476925287 / (double)SR_);
  s[t] = x;
  __syncthreads();
  for (int off = 1; off < 512; off <<= 1) {
    double v = (t >= off) ? s[t - off] : 0.0;
    __syncthreads();
    s[t] += v;
    __syncthreads();
  }
  if (t < T_) {
    Xv[b * T_ + t] = x;
    Pv[b * T_ + t] = (s[t] - x) * 160.0;
  }
}

// ---------------- K2: per-(b,t) harmonic synth + filtered noise -> packed bf16 hi/lo ----------------
__global__ __launch_bounds__(160) void k_synth(
    const float* __restrict__ pitch, const float* __restrict__ tamp,
    const float* __restrict__ harmo, const float* __restrict__ nfilt,
    const float* __restrict__ noise, const double* __restrict__ Pv,
    const double* __restrict__ Xv, unsigned short* __restrict__ PH,
    unsigned short* __restrict__ PL) {
  const int bt = blockIdx.x, b = bt / T_, t = bt - b * T_;
  const int tid = threadIdx.x;
  __shared__ float amp[NH_], sbase[NH_], sstep[NH_];
  __shared__ float a_s[NB_], ctab[128], ir_s[128], imp_s[BLK_], noi_s[BLK_], red[128];

  const float pv = pitch[b * T_ + t];
  if (tid < 128) ctab[tid] = cosf((float)tid * 0.049087385212340526f);  // 2pi/128
  if (tid < NB_) a_s[tid] = nfilt[bt * NB_ + tid];
  noi_s[tid] = noise[bt * BLK_ + tid];
  if (tid < NH_) {
    float ha = harmo[(b * NH_ + tid) * T_ + t];
    float aa = (pv * (float)(tid + 1) < 8000.0f ? 1.0f : 0.0f) + 1e-4f;
    amp[tid] = ha * aa;
  }
  __syncthreads();
  if (tid < 128) {
    float sum = 0.f;
    for (int k = 1; k < 64; ++k) sum = fmaf(a_s[k], ctab[(k * tid) & 127], sum);
    float v = a_s[0] + ((tid & 1) ? -a_s[64] : a_s[64]) + 2.f * sum;
    ir_s[tid] = v * (1.0f / 128.0f);
    red[tid] = (tid < NH_) ? amp[tid] : 0.f;
  }
  __syncthreads();
  for (int off = 64; off >= 1; off >>= 1) {
    if (tid < off) red[tid] += red[tid + off];
    __syncthreads();
  }
  const float scale = tamp[b * T_ + t] / red[0];
  if (tid < NH_) {
    amp[tid] *= scale;
    const double h = (double)(tid + 1);
    double vb = h * Pv[b * T_ + t];
    vb -= floor(vb * 0.15915494309189533577) * 6.2831853071795864769;
    sbase[tid] = (float)vb;
    double vs = h * Xv[b * T_ + t];
    vs -= floor(vs * 0.15915494309189533577) * 6.2831853071795864769;
    sstep[tid] = (float)vs;
  }
  {
    float v;
    if (tid < 64)      v = (0.5f - 0.5f * ctab[tid + 64]) * ir_s[tid];
    else if (tid < 96) v = 0.f;
    else               v = (0.5f - 0.5f * ctab[tid - 96]) * ir_s[tid - 32];
    imp_s[tid] = v;
  }
  __syncthreads();
  float nf = 0.f;
  for (int j = 0; j <= tid; ++j) nf = fmaf(noi_s[j], imp_s[tid - j], nf);
  const float fi = (float)(tid + 1);
  float acc = 0.f;
#pragma unroll 4
  for (int h = 0; h < NH_; ++h) {
    float ph = fmaf(fi, sstep[h], sbase[h]);
    ph = fmaf(-floorf(ph * 0.15915494f), 6.2831853f, ph);
    acc = fmaf(amp[h], __sinf(ph), acc);
  }
  const float v = acc + nf;
  const unsigned k = (unsigned)(KPAD_ + t * BLK_ + tid);
  const unsigned off = ((k >> 3) << 7) + ((unsigned)b << 3) + (k & 7u);
  const unsigned short h = f2bf(v);
  PH[off] = h;
  PL[off] = f2bf(v - bf2f(h));
}

// ---------------- K3: build Toeplitz A-fragment table (hi/lo bf16), reverb decay inline ----------------
// FRAG[t][lane][j] = imp[(t-6)*16 + (lane&15) - 8*(lane>>4) - j]
__global__ __launch_bounds__(512) void k_fragbuild(const float* __restrict__ rn,
                                                   const float* __restrict__ dec,
                                                   const float* __restrict__ wet,
                                                   unsigned short* __restrict__ FH,
                                                   unsigned short* __restrict__ FL) {
  const int t = blockIdx.x, tid = threadIdx.x;
  const int lane = tid >> 3, j = tid & 7;
  const int idx = (t - 6) * 16 + (lane & 15) - ((lane >> 4) << 3) - j;
  float v = 0.f;
  if (idx == 0) {
    v = 1.0f;
  } else if (idx > 0 && idx < REV_) {
    const float a = log1pf(expf(-dec[0]));
    const float sg = 1.f / (1.f + expf(-wet[0]));
    v = rn[idx] * expf(-a * ((float)idx / (float)SR_) * 500.0f) * sg;
  }
  const unsigned short h = f2bf(v);
  FH[t * 512 + tid] = h;
  FL[t * 512 + tid] = f2bf(v - bf2f(h));
}

// ---------------- K4: reverb as Toeplitz MFMA GEMM ----------------
// 4 waves per block = 4 K-splits of one 128-output tile; LDS reduce; no atomics.
static __device__ __forceinline__ f32x4 mfma_bf16(bf16x8 a, bf16x8 b, f32x4 c) {
  return __builtin_amdgcn_mfma_f32_16x16x32_bf16(a, b, c, 0, 0, 0);
}

template <int U, bool PF>
__device__ __forceinline__ void conv_step(bf16x8 (&Rh)[8], bf16x8 (&Rl)[8], f32x4 (&acc)[8],
                                          bf16x8& bhi, bf16x8& blo,
                                          const bf16x8* __restrict__ ph,
                                          const bf16x8* __restrict__ pl,
                                          const bf16x8* __restrict__ fh,
                                          const bf16x8* __restrict__ fl,
                                          int& kcur, int& tcur) {
  bf16x8 nbh, nbl, na0h, na1h, na0l, na1l;
  if (PF) {
    kcur += 64;              // +32 samples = +64 bf16x8 units
    nbh = ph[kcur]; nbl = pl[kcur];
    tcur -= 2;
    na0h = fh[tcur * 64]; na1h = fh[(tcur + 1) * 64];
    na0l = fl[tcur * 64]; na1l = fl[(tcur + 1) * 64];
  }
#pragma unroll
  for (int m = 0; m < 8; ++m) {
    const int sl = (m - 2 * U) & 7;
    acc[m] = mfma_bf16(Rh[sl], bhi, acc[m]);
    acc[m] = mfma_bf16(Rh[sl], blo, acc[m]);
    acc[m] = mfma_bf16(Rl[sl], bhi, acc[m]);
  }
  if (PF) {
    Rh[(6 - 2 * U) & 7] = na0h; Rh[(7 - 2 * U) & 7] = na1h;
    Rl[(6 - 2 * U) & 7] = na0l; Rl[(7 - 2 * U) & 7] = na1l;
    bhi = nbh; blo = nbl;
  }
}

__global__ __launch_bounds__(256) void k_mconv(const bf16x8* __restrict__ FH,
                                               const bf16x8* __restrict__ FL,
                                               const bf16x8* __restrict__ PH,
                                               const bf16x8* __restrict__ PL,
                                               float* __restrict__ out) {
  const int tid = threadIdx.x;
  const int s = tid >> 6, lane = tid & 63;
  int w = blockIdx.x;
  {  // bijective XCD swizzle, nwg=500
    const int q = 500 / 8, r = 500 % 8;
    const int xcd = w & 7, o = w >> 3;
    w = (xcd < r ? xcd * (q + 1) : r * (q + 1) + (xcd - r) * q) + o;
  }
  const int P0w = w << 7;
  const int T0 = 1006 - 252 * s;

  const bf16x8* fh = FH + lane;
  const bf16x8* fl = FL + lane;
  bf16x8 Rh[8], Rl[8];
#pragma unroll
  for (int m = 0; m < 8; ++m) {
    Rh[m] = fh[(T0 + m) * 64];
    Rl[m] = fl[(T0 + m) * 64];
  }
  f32x4 acc[8];
#pragma unroll
  for (int m = 0; m < 8; ++m) acc[m] = (f32x4){0.f, 0.f, 0.f, 0.f};

  const int K0 = P0w + 128 + s * (STEPS_ * 32);   // padded sample index at i=0
  const bf16x8* ph = PH + ((lane >> 4) << 4) + (lane & 15);
  const bf16x8* pl = PL + ((lane >> 4) << 4) + (lane & 15);

  int kcur = K0 << 1;
  int tcur = T0;
  bf16x8 bhi = ph[kcur], blo = pl[kcur];

  for (int ii = 0; ii < 31; ++ii) {   // i = 4*ii + u, covers 0..123
    conv_step<0, true>(Rh, Rl, acc, bhi, blo, ph, pl, fh, fl, kcur, tcur);
    conv_step<1, true>(Rh, Rl, acc, bhi, blo, ph, pl, fh, fl, kcur, tcur);
    conv_step<2, true>(Rh, Rl, acc, bhi, blo, ph, pl, fh, fl, kcur, tcur);
    conv_step<3, true>(Rh, Rl, acc, bhi, blo, ph, pl, fh, fl, kcur, tcur);
  }
  conv_step<0, true>(Rh, Rl, acc, bhi, blo, ph, pl, fh, fl, kcur, tcur);   // i=124
  conv_step<1, false>(Rh, Rl, acc, bhi, blo, ph, pl, fh, fl, kcur, tcur);  // i=125

  // cross-wave (K-split) reduction in LDS, then plain coalesced stores
  __shared__ f32x4 part[KSPLIT_][8][64];
#pragma unroll
  for (int m = 0; m < 8; ++m) part[s][m][lane] = acc[m];
  __syncthreads();
#pragma unroll
  for (int half = 0; half < 2; ++half) {
    const int it = tid + (half << 8);
    const int m = it >> 6, ln = it & 63;
    f32x4 v = part[0][m][ln];
    v += part[1][m][ln];
    v += part[2][m][ln];
    v += part[3][m][ln];
    const int b = ln & 15, hi2 = ln >> 4;
    const int p = P0w + (m << 4) + (hi2 << 2);
    *(f32x4*)(out + (size_t)b * N_ + p) = v;
  }
}

extern "C" void kernel_launch(void* const* d_in, const int* in_sizes, int n_in,
                              void* d_out, int out_size, void* d_ws, size_t ws_size,
                              hipStream_t stream) {
  const float* pitch = (const float*)d_in[0];
  const float* tamp  = (const float*)d_in[1];
  const float* harmo = (const float*)d_in[2];
  const float* nfilt = (const float*)d_in[3];
  const float* noise = (const float*)d_in[4];
  const float* rn    = (const float*)d_in[5];
  const float* dec   = (const float*)d_in[6];
  const float* wet   = (const float*)d_in[7];

  char* ws = (char*)d_ws;
  size_t off = 0;
  unsigned short* PH = (unsigned short*)(ws + off); off += (size_t)KTOT_ * 16 * 2;  // 2.56 MB
  unsigned short* PL = (unsigned short*)(ws + off); off += (size_t)KTOT_ * 16 * 2;
  unsigned short* FH = (unsigned short*)(ws + off); off += (size_t)NT_ * 512 * 2;   // 1.04 MB
  unsigned short* FL = (unsigned short*)(ws + off); off += (size_t)NT_ * 512 * 2;
  double* Pv = (double*)(ws + off);           off += (size_t)B_ * T_ * 8;
  double* Xv = (double*)(ws + off);           off += (size_t)B_ * T_ * 8;
  float* out = (float*)d_out;

  // zero the packed signal (front/tail pads; body overwritten by k_synth)
  hipMemsetAsync(PH, 0, (size_t)KTOT_ * 16 * 2 * 2, stream);

  k_prefix<<<dim3(B_), dim3(512), 0, stream>>>(pitch, Pv, Xv);
  k_synth<<<dim3(B_ * T_), dim3(160), 0, stream>>>(pitch, tamp, harmo, nfilt, noise, Pv, Xv, PH, PL);
  k_fragbuild<<<dim3(NT_), dim3(512), 0, stream>>>(rn, dec, wet, FH, FL);
  k_mconv<<<dim3(500), dim3(256), 0, stream>>>(
      (const bf16x8*)FH, (const bf16x8*)FL, (const bf16x8*)PH, (const bf16x8*)PL, out);
}